// Round 3
// baseline (842.785 us; speedup 1.0000x reference)
//
#include <hip/hip_runtime.h>
#include <math.h>

#define NEG_SLOPE 0.2f
__device__ __forceinline__ float lrelu(float x) { return x > 0.f ? x : NEG_SLOPE * x; }

// Order-preserving float<->uint encoding so unsigned atomicMax == float max.
// 0u is a safe bottom element (below every finite encoding).
__device__ __forceinline__ unsigned encf(float f) {
    unsigned u = __float_as_uint(f);
    return (u & 0x80000000u) ? ~u : (u | 0x80000000u);
}
__device__ __forceinline__ float decf(unsigned u) {
    return __uint_as_float((u & 0x80000000u) ? (u ^ 0x80000000u) : ~u);
}

__global__ void initK(int* __restrict__ deg, unsigned* __restrict__ gmax1,
                      unsigned* __restrict__ gmax2, int N) {
    int i = blockIdx.x * blockDim.x + threadIdx.x;
    if (i < N) deg[i] = 0;
    if (i < 4) gmax1[i] = 0u;
    if (i == 0) gmax2[0] = 0u;
}

// Phase A: h1 = x @ W1 [N,64]; alpha_src/dst [N,4]; self-loop logit.
// 64 lanes per node: lane = head*16 + c.
__global__ void phaseA(const float* __restrict__ x, const float* __restrict__ W1,
                       const float* __restrict__ a_src, const float* __restrict__ a_dst,
                       float* __restrict__ h1, float* __restrict__ asrc1,
                       float* __restrict__ adst1, float* __restrict__ eloop1, int N) {
    int node = blockIdx.x * 4 + (threadIdx.x >> 6);
    if (node >= N) return;
    int lane = threadIdx.x & 63;
    int head = lane >> 4, c = lane & 15;

    float h = 0.f;
    #pragma unroll
    for (int k = 0; k < 7; k++) h += x[node * 7 + k] * W1[k * 64 + lane];
    h1[node * 64 + lane] = h;

    float s = h * a_src[lane];
    float d = h * a_dst[lane];
    #pragma unroll
    for (int m = 8; m >= 1; m >>= 1) {
        s += __shfl_xor(s, m);
        d += __shfl_xor(d, m);
    }
    if (c == 0) {
        asrc1[node * 4 + head] = s;
        adst1[node * 4 + head] = d;
        eloop1[node * 4 + head] = lrelu(s + d);
    }
}

// Global per-head max of asrc1 [N,4] -> gmax1[4] (encoded uints).
__global__ void gmax1K(const float* __restrict__ asrc1, unsigned* __restrict__ gmax1, int N) {
    float m0 = -1e30f, m1 = -1e30f, m2 = -1e30f, m3 = -1e30f;
    for (int i = blockIdx.x * blockDim.x + threadIdx.x; i < N; i += gridDim.x * blockDim.x) {
        float4 v = ((const float4*)asrc1)[i];
        m0 = fmaxf(m0, v.x); m1 = fmaxf(m1, v.y);
        m2 = fmaxf(m2, v.z); m3 = fmaxf(m3, v.w);
    }
    #pragma unroll
    for (int mm = 32; mm >= 1; mm >>= 1) {
        m0 = fmaxf(m0, __shfl_xor(m0, mm));
        m1 = fmaxf(m1, __shfl_xor(m1, mm));
        m2 = fmaxf(m2, __shfl_xor(m2, mm));
        m3 = fmaxf(m3, __shfl_xor(m3, mm));
    }
    if ((threadIdx.x & 63) == 0) {
        atomicMax(&gmax1[0], encf(m0));
        atomicMax(&gmax1[1], encf(m1));
        atomicMax(&gmax1[2], encf(m2));
        atomicMax(&gmax1[3], encf(m3));
    }
}

// Global max of asrc2 [N] -> gmax2[1].
__global__ void gmax2K(const float* __restrict__ asrc2, unsigned* __restrict__ gmax2, int N) {
    float m0 = -1e30f;
    for (int i = blockIdx.x * blockDim.x + threadIdx.x; i < N; i += gridDim.x * blockDim.x)
        m0 = fmaxf(m0, asrc2[i]);
    #pragma unroll
    for (int mm = 32; mm >= 1; mm >>= 1) m0 = fmaxf(m0, __shfl_xor(m0, mm));
    if ((threadIdx.x & 63) == 0) atomicMax(gmax2, encf(m0));
}

__global__ void degCount(const int* __restrict__ dst, int* __restrict__ deg, int E) {
    int i = blockIdx.x * blockDim.x + threadIdx.x;
    if (i < E) atomicAdd(&deg[dst[i]], 1);
}

__global__ void scan1(const int* __restrict__ deg, int* __restrict__ rowstart,
                      int* __restrict__ blockSum, int N) {
    __shared__ int sm[256];
    int tid = threadIdx.x;
    int i = blockIdx.x * 256 + tid;
    int v = (i < N) ? deg[i] : 0;
    sm[tid] = v;
    __syncthreads();
    for (int off = 1; off < 256; off <<= 1) {
        int t = sm[tid];
        int add = (tid >= off) ? sm[tid - off] : 0;
        __syncthreads();
        sm[tid] = t + add;
        __syncthreads();
    }
    if (i < N) rowstart[i] = sm[tid] - v;     // exclusive
    if (tid == 255) blockSum[blockIdx.x] = sm[255];
}

__global__ void scan2(int* __restrict__ blockSum, int nb) {
    __shared__ int sm[1024];
    int tid = threadIdx.x;
    int v = (tid < nb) ? blockSum[tid] : 0;
    sm[tid] = v;
    __syncthreads();
    for (int off = 1; off < 1024; off <<= 1) {
        int t = sm[tid];
        int add = (tid >= off) ? sm[tid - off] : 0;
        __syncthreads();
        sm[tid] = t + add;
        __syncthreads();
    }
    if (tid < nb) blockSum[tid] = sm[tid] - v;  // exclusive
}

// scan3 also initializes cursor = rowstart (scatter bumps cursor directly).
__global__ void scan3(int* __restrict__ rowstart, int* __restrict__ cursor,
                      const int* __restrict__ blockSum, int N) {
    int i = blockIdx.x * 256 + threadIdx.x;
    if (i < N) {
        int v = rowstart[i] + blockSum[blockIdx.x];
        rowstart[i] = v;
        cursor[i] = v;
    }
}

__global__ void scatter(const int* __restrict__ src, const int* __restrict__ dst,
                        int* __restrict__ cursor, int* __restrict__ csr, int E) {
    int i = blockIdx.x * blockDim.x + threadIdx.x;
    if (i >= E) return;
    int pos = atomicAdd(&cursor[dst[i]], 1);
    csr[pos] = src[i];
}

// Layer-1 gather (single pass, bound-shifted softmax, software-pipelined),
// fused with: normalize, +b1, ELU, @W2, layer-2 logits.
__global__ void gatherL1(const int* __restrict__ csr, const int* __restrict__ rowstart,
                         const int* __restrict__ deg, const unsigned* __restrict__ gmax1,
                         const float* __restrict__ h1, const float* __restrict__ asrc1,
                         const float* __restrict__ adst1, const float* __restrict__ eloop1,
                         const float* __restrict__ b1, const float* __restrict__ W2,
                         const float* __restrict__ a_src2, const float* __restrict__ a_dst2,
                         float* __restrict__ h2, float* __restrict__ asrc2,
                         float* __restrict__ adst2, float* __restrict__ eloop2, int N) {
    int node = blockIdx.x * 4 + (threadIdx.x >> 6);
    if (node >= N) return;
    int lane = threadIdx.x & 63;
    int head = lane >> 4;
    int rs = rowstart[node], dg = deg[node];
    int ke = rs + dg;

    float adh = adst1[node * 4 + head];
    float el = eloop1[node * 4 + head];
    float m = lrelu(decf(gmax1[head]) + adh);   // upper bound on segment logits

    float z0 = __expf(el - m);
    float den = z0;
    float acc = z0 * h1[node * 64 + lane];

    if (dg > 0) {
        // pipelined: csr prefetched 2 ahead, asrc/h1 values 1 ahead
        int s = csr[rs];
        int s_nxt = csr[dg > 1 ? rs + 1 : rs];
        float av = asrc1[s * 4 + head];
        float hv = h1[s * 64 + lane];
        for (int k = rs; k < ke; k++) {
            int s2 = s_nxt;
            int kk = (k + 2 < ke) ? k + 2 : ke - 1;
            s_nxt = csr[kk];
            float av2 = asrc1[s2 * 4 + head];
            float hv2 = h1[s2 * 64 + lane];
            float z = __expf(lrelu(av + adh) - m);
            den += z;
            acc = fmaf(z, hv, acc);
            av = av2; hv = hv2;
        }
    }

    float v = acc / den + b1[lane];
    v = v > 0.f ? v : __expf(v) - 1.f;  // ELU

    // fused: h2 = v @ W2 (64->6) via full-wave shfl reductions
    float hh[6];
    #pragma unroll
    for (int c2 = 0; c2 < 6; c2++) {
        float p = v * W2[lane * 6 + c2];
        #pragma unroll
        for (int mm = 32; mm >= 1; mm >>= 1) p += __shfl_xor(p, mm);
        hh[c2] = p;
    }
    float as = 0.f, ad = 0.f;
    #pragma unroll
    for (int c2 = 0; c2 < 6; c2++) {
        as += hh[c2] * a_src2[c2];
        ad += hh[c2] * a_dst2[c2];
    }
    if (lane == 0) {
        #pragma unroll
        for (int c2 = 0; c2 < 6; c2++) h2[node * 6 + c2] = hh[c2];
        asrc2[node] = as;
        adst2[node] = ad;
        eloop2[node] = lrelu(as + ad);
    }
}

// Layer-2 gather + log_softmax. Wave per node; 8 lanes per edge (cc = lane&7,
// 6 active channels), 8 edges in flight per iteration.
__global__ void gatherL2(const int* __restrict__ csr, const int* __restrict__ rowstart,
                         const int* __restrict__ deg, const unsigned* __restrict__ gmax2,
                         const float* __restrict__ h2, const float* __restrict__ asrc2,
                         const float* __restrict__ adst2, const float* __restrict__ eloop2,
                         const float* __restrict__ b2, float* __restrict__ out, int N) {
    int node = blockIdx.x * 4 + (threadIdx.x >> 6);
    if (node >= N) return;
    int lane = threadIdx.x & 63;
    int g = lane >> 3, cc = lane & 7;
    int rs = rowstart[node], dg = deg[node];
    int ke = rs + dg;

    float adn = adst2[node];
    float el = eloop2[node];
    float m = lrelu(decf(*gmax2) + adn);

    float den = 0.f, acc = 0.f;
    if (g == 0) {
        float z0 = __expf(el - m);
        if (cc == 0) den = z0;
        if (cc < 6) acc = z0 * h2[node * 6 + cc];
    }
    for (int k0 = rs; k0 < ke; k0 += 8) {
        int k = k0 + g;
        bool valid = k < ke;
        int s = csr[valid ? k : ke - 1];
        float z = valid ? __expf(lrelu(asrc2[s] + adn) - m) : 0.f;
        if (cc == 0) den += z;
        if (cc < 6) acc = fmaf(z, h2[s * 6 + cc], acc);
    }
    // fold the 8 edge-groups together (every lane ends with its cc's total)
    #pragma unroll
    for (int mm = 32; mm >= 8; mm >>= 1) acc += __shfl_xor(acc, mm);
    // den: full 64-lane sum
    #pragma unroll
    for (int mm = 32; mm >= 1; mm >>= 1) den += __shfl_xor(den, mm);

    float v = (cc < 6) ? (acc / den + b2[cc]) : -1e30f;
    // log_softmax across the 6 channel lanes of each 8-lane group
    float mxv = v;
    #pragma unroll
    for (int mm = 4; mm >= 1; mm >>= 1) mxv = fmaxf(mxv, __shfl_xor(mxv, mm));
    float ex = (cc < 6) ? __expf(v - mxv) : 0.f;
    float ssum = ex;
    #pragma unroll
    for (int mm = 4; mm >= 1; mm >>= 1) ssum += __shfl_xor(ssum, mm);
    if (g == 0 && cc < 6) out[node * 6 + cc] = v - mxv - logf(ssum);
}

extern "C" void kernel_launch(void* const* d_in, const int* in_sizes, int n_in,
                              void* d_out, int out_size, void* d_ws, size_t ws_size,
                              hipStream_t stream) {
    const float* x      = (const float*)d_in[0];
    const int*   ei     = (const int*)d_in[1];
    const float* W1     = (const float*)d_in[2];
    const float* a_src1 = (const float*)d_in[3];
    const float* a_dst1 = (const float*)d_in[4];
    const float* b1     = (const float*)d_in[5];
    const float* W2     = (const float*)d_in[6];
    const float* a_src2 = (const float*)d_in[7];
    const float* a_dst2 = (const float*)d_in[8];
    const float* b2     = (const float*)d_in[9];
    float* out = (float*)d_out;

    const int N = in_sizes[0] / 7;
    const int E = in_sizes[1] / 2;
    const int* src = ei;
    const int* dst = ei + E;

    // Workspace layout
    float* w = (float*)d_ws;
    float* h1     = w;  w += (size_t)N * 64;
    float* asrc1  = w;  w += (size_t)N * 4;
    float* adst1  = w;  w += (size_t)N * 4;
    float* eloop1 = w;  w += (size_t)N * 4;
    float* h2     = w;  w += (size_t)N * 6;
    float* asrc2  = w;  w += (size_t)N;
    float* adst2  = w;  w += (size_t)N;
    float* eloop2 = w;  w += (size_t)N;
    int* ip = (int*)w;
    int* deg      = ip; ip += N;
    int* cursor   = ip; ip += N;
    int* rowstart = ip; ip += N;
    int* blockSum = ip; ip += 1024;
    int* csr      = ip; ip += E;
    unsigned* gmax1 = (unsigned*)ip; ip += 4;
    unsigned* gmax2 = (unsigned*)ip; ip += 4;

    const int B = 256;
    dim3 gNode((N + 3) / 4);
    dim3 gE((E + B - 1) / B);
    dim3 gScan((N + 255) / 256);
    int nb = (N + 255) / 256;

    initK<<<(N + B - 1) / B, B, 0, stream>>>(deg, gmax1, gmax2, N);
    phaseA<<<gNode, B, 0, stream>>>(x, W1, a_src1, a_dst1, h1, asrc1, adst1, eloop1, N);
    gmax1K<<<128, B, 0, stream>>>(asrc1, gmax1, N);
    degCount<<<gE, B, 0, stream>>>(dst, deg, E);
    scan1<<<gScan, 256, 0, stream>>>(deg, rowstart, blockSum, N);
    scan2<<<1, 1024, 0, stream>>>(blockSum, nb);
    scan3<<<gScan, 256, 0, stream>>>(rowstart, cursor, blockSum, N);
    scatter<<<gE, B, 0, stream>>>(src, dst, cursor, csr, E);
    gatherL1<<<gNode, B, 0, stream>>>(csr, rowstart, deg, gmax1, h1, asrc1, adst1, eloop1,
                                      b1, W2, a_src2, a_dst2,
                                      h2, asrc2, adst2, eloop2, N);
    gmax2K<<<128, B, 0, stream>>>(asrc2, gmax2, N);
    gatherL2<<<gNode, B, 0, stream>>>(csr, rowstart, deg, gmax2, h2, asrc2, adst2, eloop2,
                                      b2, out, N);
}

// Round 4
// 666.101 us; speedup vs baseline: 1.2653x; 1.2653x over previous
//
#include <hip/hip_runtime.h>
#include <math.h>

#define NEG_SLOPE 0.2f
__device__ __forceinline__ float lrelu(float x) { return x > 0.f ? x : NEG_SLOPE * x; }

// Order-preserving float<->uint encoding so unsigned atomicMax == float max.
__device__ __forceinline__ unsigned encf(float f) {
    unsigned u = __float_as_uint(f);
    return (u & 0x80000000u) ? ~u : (u | 0x80000000u);
}
__device__ __forceinline__ float decf(unsigned u) {
    return __uint_as_float((u & 0x80000000u) ? (u ^ 0x80000000u) : ~u);
}

__global__ void initK(int* __restrict__ deg, unsigned* __restrict__ gmax1,
                      unsigned* __restrict__ gmax2, int N) {
    int i = blockIdx.x * blockDim.x + threadIdx.x;
    if (i < N) deg[i] = 0;
    if (i < 4) gmax1[i] = 0u;
    if (i == 0) gmax2[0] = 0u;
}

// Phase A: h1 = x @ W1 [N,64]; alpha_src/dst [N,4]; self-loop logit.
__global__ void phaseA(const float* __restrict__ x, const float* __restrict__ W1,
                       const float* __restrict__ a_src, const float* __restrict__ a_dst,
                       float* __restrict__ h1, float* __restrict__ asrc1,
                       float* __restrict__ adst1, float* __restrict__ eloop1, int N) {
    int node = blockIdx.x * 4 + (threadIdx.x >> 6);
    if (node >= N) return;
    int lane = threadIdx.x & 63;
    int head = lane >> 4, c = lane & 15;

    float h = 0.f;
    #pragma unroll
    for (int k = 0; k < 7; k++) h += x[node * 7 + k] * W1[k * 64 + lane];
    h1[node * 64 + lane] = h;

    float s = h * a_src[lane];
    float d = h * a_dst[lane];
    #pragma unroll
    for (int m = 8; m >= 1; m >>= 1) {
        s += __shfl_xor(s, m);
        d += __shfl_xor(d, m);
    }
    if (c == 0) {
        asrc1[node * 4 + head] = s;
        adst1[node * 4 + head] = d;
        eloop1[node * 4 + head] = lrelu(s + d);
    }
}

// Global per-head max of asrc1 [N,4] -> gmax1[4] (encoded).
__global__ void gmax1K(const float* __restrict__ asrc1, unsigned* __restrict__ gmax1, int N) {
    float m0 = -1e30f, m1 = -1e30f, m2 = -1e30f, m3 = -1e30f;
    for (int i = blockIdx.x * blockDim.x + threadIdx.x; i < N; i += gridDim.x * blockDim.x) {
        float4 v = ((const float4*)asrc1)[i];
        m0 = fmaxf(m0, v.x); m1 = fmaxf(m1, v.y);
        m2 = fmaxf(m2, v.z); m3 = fmaxf(m3, v.w);
    }
    #pragma unroll
    for (int mm = 32; mm >= 1; mm >>= 1) {
        m0 = fmaxf(m0, __shfl_xor(m0, mm));
        m1 = fmaxf(m1, __shfl_xor(m1, mm));
        m2 = fmaxf(m2, __shfl_xor(m2, mm));
        m3 = fmaxf(m3, __shfl_xor(m3, mm));
    }
    if ((threadIdx.x & 63) == 0) {
        atomicMax(&gmax1[0], encf(m0));
        atomicMax(&gmax1[1], encf(m1));
        atomicMax(&gmax1[2], encf(m2));
        atomicMax(&gmax1[3], encf(m3));
    }
}

__global__ void gmax2K(const float* __restrict__ asrc2, unsigned* __restrict__ gmax2, int N) {
    float m0 = -1e30f;
    for (int i = blockIdx.x * blockDim.x + threadIdx.x; i < N; i += gridDim.x * blockDim.x)
        m0 = fmaxf(m0, asrc2[i]);
    #pragma unroll
    for (int mm = 32; mm >= 1; mm >>= 1) m0 = fmaxf(m0, __shfl_xor(m0, mm));
    if ((threadIdx.x & 63) == 0) atomicMax(gmax2, encf(m0));
}

__global__ void degCount(const int* __restrict__ dst, int* __restrict__ deg, int E) {
    int i = blockIdx.x * blockDim.x + threadIdx.x;
    if (i < E) atomicAdd(&deg[dst[i]], 1);
}

__global__ void scan1(const int* __restrict__ deg, int* __restrict__ rowstart,
                      int* __restrict__ blockSum, int N) {
    __shared__ int sm[256];
    int tid = threadIdx.x;
    int i = blockIdx.x * 256 + tid;
    int v = (i < N) ? deg[i] : 0;
    sm[tid] = v;
    __syncthreads();
    for (int off = 1; off < 256; off <<= 1) {
        int t = sm[tid];
        int add = (tid >= off) ? sm[tid - off] : 0;
        __syncthreads();
        sm[tid] = t + add;
        __syncthreads();
    }
    if (i < N) rowstart[i] = sm[tid] - v;     // exclusive
    if (tid == 255) blockSum[blockIdx.x] = sm[255];
}

__global__ void scan2(int* __restrict__ blockSum, int nb) {
    __shared__ int sm[1024];
    int tid = threadIdx.x;
    int v = (tid < nb) ? blockSum[tid] : 0;
    sm[tid] = v;
    __syncthreads();
    for (int off = 1; off < 1024; off <<= 1) {
        int t = sm[tid];
        int add = (tid >= off) ? sm[tid - off] : 0;
        __syncthreads();
        sm[tid] = t + add;
        __syncthreads();
    }
    if (tid < nb) blockSum[tid] = sm[tid] - v;  // exclusive
}

__global__ void scan3(int* __restrict__ rowstart, int* __restrict__ cursor,
                      const int* __restrict__ blockSum, int N) {
    int i = blockIdx.x * 256 + threadIdx.x;
    if (i < N) {
        int v = rowstart[i] + blockSum[blockIdx.x];
        rowstart[i] = v;
        cursor[i] = v;
    }
}

__global__ void scatter(const int* __restrict__ src, const int* __restrict__ dst,
                        int* __restrict__ cursor, int* __restrict__ csr, int E) {
    int i = blockIdx.x * blockDim.x + threadIdx.x;
    if (i >= E) return;
    int pos = atomicAdd(&cursor[dst[i]], 1);
    csr[pos] = src[i];
}

// Layer-1 gather: 16 lanes per node (lane t owns channels 4t..4t+3, head=t>>2),
// 4 nodes per wave -> 4 independent gather streams. Single pass (gmax bound).
// Fused epilogue: normalize, +b1, ELU, @W2, layer-2 logits, pack h2pad row.
__global__ void gatherL1(const int* __restrict__ csr, const int* __restrict__ rowstart,
                         const int* __restrict__ deg, const unsigned* __restrict__ gmax1,
                         const float* __restrict__ h1, const float* __restrict__ asrc1,
                         const float* __restrict__ adst1, const float* __restrict__ eloop1,
                         const float* __restrict__ b1, const float* __restrict__ W2,
                         const float* __restrict__ a_src2, const float* __restrict__ a_dst2,
                         float* __restrict__ h2pad, float* __restrict__ asrc2,
                         float* __restrict__ adst2, float* __restrict__ eloop2, int N) {
    int node = blockIdx.x * 16 + (threadIdx.x >> 4);
    if (node >= N) return;
    int t = threadIdx.x & 15;
    int head = t >> 2;

    int rs = rowstart[node], dg = deg[node];
    float adh = adst1[node * 4 + head];
    float el = eloop1[node * 4 + head];
    float m = lrelu(decf(gmax1[head]) + adh);   // upper bound on segment logits

    const float4* h1v = (const float4*)h1;      // h1 as [N][16] of float4
    float z0 = __expf(el - m);
    float den = z0;
    float4 hv0 = h1v[(size_t)node * 16 + t];
    float ax = z0 * hv0.x, ay = z0 * hv0.y, az = z0 * hv0.z, aw = z0 * hv0.w;

    if (dg > 0) {
        int s = csr[rs];
        for (int k = rs; k < rs + dg; ++k) {
            int kk = (k + 1 < rs + dg) ? k + 1 : k;
            int s_next = csr[kk];
            float av = asrc1[s * 4 + head];
            float4 hv = h1v[(size_t)s * 16 + t];
            float z = __expf(lrelu(av + adh) - m);
            den += z;
            ax = fmaf(z, hv.x, ax); ay = fmaf(z, hv.y, ay);
            az = fmaf(z, hv.z, az); aw = fmaf(z, hv.w, aw);
            s = s_next;
        }
    }

    float inv = 1.f / den;
    float4 bv = ((const float4*)b1)[t];
    float v0 = ax * inv + bv.x, v1 = ay * inv + bv.y;
    float v2 = az * inv + bv.z, v3 = aw * inv + bv.w;
    v0 = v0 > 0.f ? v0 : __expf(v0) - 1.f;
    v1 = v1 > 0.f ? v1 : __expf(v1) - 1.f;
    v2 = v2 > 0.f ? v2 : __expf(v2) - 1.f;
    v3 = v3 > 0.f ? v3 : __expf(v3) - 1.f;

    // h2 = v @ W2 (64->6): per-lane partial over 4 channels, reduce over 16 lanes
    float hh[6];
    #pragma unroll
    for (int c2 = 0; c2 < 6; c2++) {
        float p = v0 * W2[(t * 4 + 0) * 6 + c2] + v1 * W2[(t * 4 + 1) * 6 + c2]
                + v2 * W2[(t * 4 + 2) * 6 + c2] + v3 * W2[(t * 4 + 3) * 6 + c2];
        #pragma unroll
        for (int mm = 8; mm >= 1; mm >>= 1) p += __shfl_xor(p, mm);
        hh[c2] = p;
    }
    float as = 0.f, ad = 0.f;
    #pragma unroll
    for (int c2 = 0; c2 < 6; c2++) {
        as += hh[c2] * a_src2[c2];
        ad += hh[c2] * a_dst2[c2];
    }
    if (t == 0) {
        #pragma unroll
        for (int c2 = 0; c2 < 6; c2++) h2pad[(size_t)node * 8 + c2] = hh[c2];
        h2pad[(size_t)node * 8 + 6] = as;   // asrc2 packed into the gather row
        asrc2[node] = as;
        adst2[node] = ad;
        eloop2[node] = lrelu(as + ad);
    }
}

// Layer-2 gather + log_softmax. Wave per node, lane per edge (64 in flight).
// One 32B gather per edge (h2pad row holds h2[0..5] and asrc2).
__global__ void gatherL2(const int* __restrict__ csr, const int* __restrict__ rowstart,
                         const int* __restrict__ deg, const unsigned* __restrict__ gmax2,
                         const float* __restrict__ h2pad, const float* __restrict__ adst2,
                         const float* __restrict__ eloop2,
                         const float* __restrict__ b2, float* __restrict__ out, int N) {
    int node = blockIdx.x * 4 + (threadIdx.x >> 6);
    if (node >= N) return;
    int lane = threadIdx.x & 63;
    int rs = rowstart[node], ke = rs + deg[node];

    float adn = adst2[node];
    float m = lrelu(decf(*gmax2) + adn);

    float den = 0.f;
    float a0 = 0.f, a1 = 0.f, a2 = 0.f, a3 = 0.f, a4 = 0.f, a5 = 0.f;
    if (lane == 0) {
        float z0 = __expf(eloop2[node] - m);
        den = z0;
        float4 lo = ((const float4*)h2pad)[(size_t)node * 2];
        float4 hi = ((const float4*)h2pad)[(size_t)node * 2 + 1];
        a0 = z0 * lo.x; a1 = z0 * lo.y; a2 = z0 * lo.z;
        a3 = z0 * lo.w; a4 = z0 * hi.x; a5 = z0 * hi.y;
    }
    for (int k = rs + lane; k < ke; k += 64) {
        int s = csr[k];
        float4 lo = ((const float4*)h2pad)[(size_t)s * 2];
        float4 hi = ((const float4*)h2pad)[(size_t)s * 2 + 1];
        float z = __expf(lrelu(hi.z + adn) - m);   // hi.z = asrc2[s]
        den += z;
        a0 = fmaf(z, lo.x, a0); a1 = fmaf(z, lo.y, a1); a2 = fmaf(z, lo.z, a2);
        a3 = fmaf(z, lo.w, a3); a4 = fmaf(z, hi.x, a4); a5 = fmaf(z, hi.y, a5);
    }
    #pragma unroll
    for (int mm = 32; mm >= 1; mm >>= 1) {
        den += __shfl_xor(den, mm);
        a0 += __shfl_xor(a0, mm); a1 += __shfl_xor(a1, mm); a2 += __shfl_xor(a2, mm);
        a3 += __shfl_xor(a3, mm); a4 += __shfl_xor(a4, mm); a5 += __shfl_xor(a5, mm);
    }
    if (lane == 0) {
        float inv = 1.f / den;
        float v[6] = { a0 * inv + b2[0], a1 * inv + b2[1], a2 * inv + b2[2],
                       a3 * inv + b2[3], a4 * inv + b2[4], a5 * inv + b2[5] };
        float mxv = -1e30f;
        #pragma unroll
        for (int cc = 0; cc < 6; cc++) mxv = fmaxf(mxv, v[cc]);
        float ssum = 0.f;
        #pragma unroll
        for (int cc = 0; cc < 6; cc++) ssum += __expf(v[cc] - mxv);
        float lse = mxv + logf(ssum);
        #pragma unroll
        for (int cc = 0; cc < 6; cc++) out[node * 6 + cc] = v[cc] - lse;
    }
}

extern "C" void kernel_launch(void* const* d_in, const int* in_sizes, int n_in,
                              void* d_out, int out_size, void* d_ws, size_t ws_size,
                              hipStream_t stream) {
    const float* x      = (const float*)d_in[0];
    const int*   ei     = (const int*)d_in[1];
    const float* W1     = (const float*)d_in[2];
    const float* a_src1 = (const float*)d_in[3];
    const float* a_dst1 = (const float*)d_in[4];
    const float* b1     = (const float*)d_in[5];
    const float* W2     = (const float*)d_in[6];
    const float* a_src2 = (const float*)d_in[7];
    const float* a_dst2 = (const float*)d_in[8];
    const float* b2     = (const float*)d_in[9];
    float* out = (float*)d_out;

    const int N = in_sizes[0] / 7;
    const int E = in_sizes[1] / 2;
    const int* src = ei;
    const int* dst = ei + E;

    // Workspace layout (all float4-aligned segments)
    float* w = (float*)d_ws;
    float* h1     = w;  w += (size_t)N * 64;
    float* asrc1  = w;  w += (size_t)N * 4;
    float* adst1  = w;  w += (size_t)N * 4;
    float* eloop1 = w;  w += (size_t)N * 4;
    float* h2pad  = w;  w += (size_t)N * 8;
    float* asrc2  = w;  w += (size_t)N;
    float* adst2  = w;  w += (size_t)N;
    float* eloop2 = w;  w += (size_t)N;
    int* ip = (int*)w;
    int* deg      = ip; ip += N;
    int* cursor   = ip; ip += N;
    int* rowstart = ip; ip += N;
    int* blockSum = ip; ip += 1024;
    int* csr      = ip; ip += E;
    unsigned* gmax1 = (unsigned*)ip; ip += 4;
    unsigned* gmax2 = (unsigned*)ip; ip += 4;

    const int B = 256;
    dim3 gE((E + B - 1) / B);
    dim3 gScan((N + 255) / 256);
    int nb = (N + 255) / 256;

    initK<<<(N + B - 1) / B, B, 0, stream>>>(deg, gmax1, gmax2, N);
    phaseA<<<dim3((N + 3) / 4), B, 0, stream>>>(x, W1, a_src1, a_dst1, h1, asrc1, adst1, eloop1, N);
    gmax1K<<<128, B, 0, stream>>>(asrc1, gmax1, N);
    degCount<<<gE, B, 0, stream>>>(dst, deg, E);
    scan1<<<gScan, 256, 0, stream>>>(deg, rowstart, blockSum, N);
    scan2<<<1, 1024, 0, stream>>>(blockSum, nb);
    scan3<<<gScan, 256, 0, stream>>>(rowstart, cursor, blockSum, N);
    scatter<<<gE, B, 0, stream>>>(src, dst, cursor, csr, E);
    gatherL1<<<dim3((N + 15) / 16), B, 0, stream>>>(csr, rowstart, deg, gmax1,
                                                    h1, asrc1, adst1, eloop1,
                                                    b1, W2, a_src2, a_dst2,
                                                    h2pad, asrc2, adst2, eloop2, N);
    gmax2K<<<128, B, 0, stream>>>(asrc2, gmax2, N);
    gatherL2<<<dim3((N + 3) / 4), B, 0, stream>>>(csr, rowstart, deg, gmax2,
                                                  h2pad, adst2, eloop2, b2, out, N);
}